// Round 14
// baseline (368.482 us; speedup 1.0000x reference)
//
#include <hip/hip_runtime.h>
#include <cstdint>

#define BB 32
#define HH 4096
#define FF 4096
#define EE 8
#define NSLOT 16   // 8 experts x 2 slots of <=16 tokens
#define TSEG 16
#define CH 1024    // rows staged per chunk (64 KB)
#define RSTR 36    // reduce stride NT16 (floats)
#define RSTR8 18   // reduce stride NT8
#define LDSB 65536 // dynamic LDS bytes

// ---------------------------------------------------------------- gate ----
__global__ __launch_bounds__(256) void gate_kernel(const float* __restrict__ x,
                                                   const float* __restrict__ Wg,
                                                   float* __restrict__ logits) {
  int b = blockIdx.x;
  int tid = threadIdx.x;
  float acc[EE];
#pragma unroll
  for (int e = 0; e < EE; ++e) acc[e] = 0.f;
  const float* xb = x + (size_t)b * HH;
  for (int h = tid; h < HH; h += 256) {
    float xv = xb[h];
    const float4* wg = (const float4*)(Wg + (size_t)h * EE);
    float4 w0 = wg[0], w1 = wg[1];
    acc[0] = fmaf(xv, w0.x, acc[0]);
    acc[1] = fmaf(xv, w0.y, acc[1]);
    acc[2] = fmaf(xv, w0.z, acc[2]);
    acc[3] = fmaf(xv, w0.w, acc[3]);
    acc[4] = fmaf(xv, w1.x, acc[4]);
    acc[5] = fmaf(xv, w1.y, acc[5]);
    acc[6] = fmaf(xv, w1.z, acc[6]);
    acc[7] = fmaf(xv, w1.w, acc[7]);
  }
#pragma unroll
  for (int off = 32; off > 0; off >>= 1) {
#pragma unroll
    for (int e = 0; e < EE; ++e) acc[e] += __shfl_down(acc[e], off, 64);
  }
  __shared__ float part[4][EE];
  if ((tid & 63) == 0) {
#pragma unroll
    for (int e = 0; e < EE; ++e) part[tid >> 6][e] = acc[e];
  }
  __syncthreads();
  if (tid < EE) {
    logits[(size_t)b * EE + tid] =
        part[0][tid] + part[1][tid] + part[2][tid] + part[3][tid];
  }
}

// --------------------------------------------------------------- route ----
__global__ void route_kernel(const float* __restrict__ logits,
                             int* __restrict__ cnt,
                             int* __restrict__ tok,
                             float* __restrict__ wts,
                             int* __restrict__ ord) {
  if (threadIdx.x != 0 || blockIdx.x != 0) return;
  int e0[BB], e1[BB];
  float p0[BB], p1[BB];
  for (int b = 0; b < BB; ++b) {
    const float* L = logits + (size_t)b * EE;
    int i0 = 0;
    float v0 = L[0];
    for (int e = 1; e < EE; ++e) {
      float v = L[e];
      if (v > v0) { v0 = v; i0 = e; }
    }
    int i1 = (i0 == 0) ? 1 : 0;
    float v1 = L[i1];
    for (int e = 0; e < EE; ++e) {
      if (e == i0) continue;
      float v = L[e];
      if (v > v1) { v1 = v; i1 = e; }
    }
    float p = 1.f / (1.f + __expf(v1 - v0));
    e0[b] = i0; e1[b] = i1; p0[b] = p; p1[b] = 1.f - p;
  }
  for (int s = 0; s < NSLOT; ++s) {
    cnt[s] = 0;
    for (int t = 0; t < TSEG; ++t) { tok[s * TSEG + t] = 0; wts[s * TSEG + t] = 0.f; }
  }
  for (int e = 0; e < EE; ++e) {
    int c = 0;
    for (int b = 0; b < BB; ++b) {
      float w = 0.f;
      int sel = 0;
      if (e0[b] == e) { w = p0[b]; sel = 1; }
      else if (e1[b] == e) { w = p1[b]; sel = 1; }
      if (sel) {
        int s = e * 2 + (c >> 4);
        int t = c & 15;
        tok[s * TSEG + t] = b;
        wts[s * TSEG + t] = w;
        cnt[s] = t + 1;
        ++c;
      }
    }
  }
  int na = 0;
  for (int s = 0; s < NSLOT; ++s) if (cnt[s] > 0) ord[na++] = s;
  for (int s = 0; s < NSLOT; ++s) if (cnt[s] == 0) ord[na++] = s;
}

// -------------------------------------------------------------- buildx ----
__global__ __launch_bounds__(256) void buildx_kernel(const float* __restrict__ x,
                                                     const int* __restrict__ cnt,
                                                     const int* __restrict__ tok,
                                                     float* __restrict__ xseg) {
  int s = blockIdx.y;
  int c = cnt[s];
  if (c == 0) return;
  int tid = threadIdx.x;
  int t = tid & 15;
  int hoff = tid >> 4;
  int tk = tok[s * TSEG + t];
  bool act = t < c;
  int hbase = blockIdx.x * 256;
#pragma unroll
  for (int i = 0; i < 16; ++i) {
    int h = hbase + i * 16 + hoff;
    float v = act ? x[(size_t)tk * HH + h] : 0.f;
    xseg[((size_t)s * HH + h) * TSEG + t] = v;
  }
}

// ------------------------------------------------------ core math NT16 ----
__device__ __forceinline__ void fma8(float4* __restrict__ acc,
                                     const float* __restrict__ xr, float4 wv) {
  float xs[8];
  *(float4*)&xs[0] = *(const float4*)(xr);
  *(float4*)&xs[4] = *(const float4*)(xr + 4);
#pragma unroll
  for (int t = 0; t < 8; ++t) {
    acc[t].x = fmaf(xs[t], wv.x, acc[t].x);
    acc[t].y = fmaf(xs[t], wv.y, acc[t].y);
    acc[t].z = fmaf(xs[t], wv.z, acc[t].z);
    acc[t].w = fmaf(xs[t], wv.w, acc[t].w);
  }
}

// 256 rows per wave per chunk, depth-16 float4 weight ring (vmcnt only);
// xs = 2 b128 broadcast reads per row from LDS (lgkmcnt).
__device__ __forceinline__ void accum256(float4* __restrict__ acc,
                                         const float4* __restrict__ wp4,
                                         const float* __restrict__ lxw,
                                         int half8) {
  float4 ring[16];
#pragma unroll
  for (int k = 0; k < 16; ++k) ring[k] = wp4[(size_t)k * 1024];
  for (int i0 = 0; i0 + 16 < 256; i0 += 16) {
#pragma unroll
    for (int k = 0; k < 16; ++k) {
      float4 wv = ring[k];
      ring[k] = wp4[(size_t)(i0 + 16 + k) * 1024];
      fma8(acc, lxw + (i0 + k) * TSEG + half8, wv);
    }
  }
#pragma unroll
  for (int k = 0; k < 16; ++k)
    fma8(acc, lxw + (240 + k) * TSEG + half8, ring[k]);
}

// ------------------------------------------------------- core math NT8 ----
__device__ __forceinline__ void fma8_2(float2* __restrict__ acc,
                                       const float* __restrict__ xr, float2 wv) {
  float xs[8];
  *(float4*)&xs[0] = *(const float4*)(xr);
  *(float4*)&xs[4] = *(const float4*)(xr + 4);
#pragma unroll
  for (int t = 0; t < 8; ++t) {
    acc[t].x = fmaf(xs[t], wv.x, acc[t].x);
    acc[t].y = fmaf(xs[t], wv.y, acc[t].y);
  }
}

__device__ __forceinline__ void accum256_8(float2* __restrict__ acc,
                                           const float2* __restrict__ wp2,
                                           const float* __restrict__ lxw) {
  float2 ring[16];
#pragma unroll
  for (int k = 0; k < 16; ++k) ring[k] = wp2[(size_t)k * 2048];
  for (int i0 = 0; i0 + 16 < 256; i0 += 16) {
#pragma unroll
    for (int k = 0; k < 16; ++k) {
      float2 wv = ring[k];
      ring[k] = wp2[(size_t)(i0 + 16 + k) * 2048];
      fma8_2(acc, lxw + (i0 + k) * TSEG, wv);
    }
  }
#pragma unroll
  for (int k = 0; k < 16; ++k)
    fma8_2(acc, lxw + (240 + k) * TSEG, ring[k]);
}

// ---------------------------------------------------------------- stage ----
// CH=1024 rows x 16 floats (linear 64 KB copy, coalesced).
__device__ __forceinline__ void stage1024(float* __restrict__ lx,
                                          const float* __restrict__ src, int tid) {
  const float4* s4 = (const float4*)src;
  float4* d4 = (float4*)lx;
#pragma unroll
  for (int k = 0; k < 16; ++k) d4[k * 256 + tid] = s4[k * 256 + tid];
}

__device__ __forceinline__ void stage_silu1024(float* __restrict__ lx,
                                               const float* __restrict__ h1p,
                                               const float* __restrict__ h3p, int tid) {
  const float4* a4 = (const float4*)h1p;
  const float4* b4 = (const float4*)h3p;
  float4* d4 = (float4*)lx;
#pragma unroll
  for (int k = 0; k < 16; ++k) {
    float4 a = a4[k * 256 + tid];
    float4 b = b4[k * 256 + tid];
    float4 g;
    g.x = (a.x / (1.f + __expf(-a.x))) * b.x;
    g.y = (a.y / (1.f + __expf(-a.y))) * b.y;
    g.z = (a.z / (1.f + __expf(-a.z))) * b.z;
    g.w = (a.w / (1.f + __expf(-a.w))) * b.w;
    d4[k * 256 + tid] = g;
  }
}

// ------------------------------------------------------- reduce (NT16) ----
__device__ __forceinline__ void red_write(float* __restrict__ lds,
                                          const float4* __restrict__ acc, int tid) {
  int l = tid & 63;
  int w = tid >> 6;
  float tmp[32];
#pragma unroll
  for (int t = 0; t < 8; ++t) {
    tmp[t] = acc[t].x;
    tmp[8 + t] = acc[t].y;
    tmp[16 + t] = acc[t].z;
    tmp[24 + t] = acc[t].w;
  }
  float* rp = lds + (size_t)(w * 64 + l) * RSTR;
#pragma unroll
  for (int q = 0; q < 32; q += 4) *(float4*)(rp + q) = *(const float4*)&tmp[q];
}

__device__ __forceinline__ void red_read(const float* __restrict__ lds,
                                         float* __restrict__ v, int tid) {
  int col = tid & 127;
  int half = tid >> 7;
  int base = (half * 32 + (col >> 2)) * RSTR + (col & 3) * 8;
#pragma unroll
  for (int t = 0; t < 8; ++t) {
    float sum = 0.f;
#pragma unroll
    for (int w = 0; w < 4; ++w) sum += lds[w * 64 * RSTR + base + t];
    v[t] = sum;
  }
}

// -------------------------------------------------------- reduce (NT8) ----
__device__ __forceinline__ void red_write8(float* __restrict__ lds,
                                           const float2* __restrict__ acc, int tid) {
  int l = tid & 63;
  int w = tid >> 6;
  float tmp[16];
#pragma unroll
  for (int t = 0; t < 8; ++t) {
    tmp[t] = acc[t].x;
    tmp[8 + t] = acc[t].y;
  }
  float* rp = lds + (size_t)(w * 64 + l) * RSTR8;
#pragma unroll
  for (int q = 0; q < 16; q += 4) *(float4*)(rp + q) = *(const float4*)&tmp[q];
}

__device__ __forceinline__ void red_read8(const float* __restrict__ lds,
                                          float* __restrict__ v, int col) {
  int base = (col >> 1) * RSTR8 + (col & 1) * 8;
#pragma unroll
  for (int t = 0; t < 8; ++t) {
    float sum = 0.f;
#pragma unroll
    for (int w = 0; w < 4; ++w) sum += lds[w * 64 * RSTR8 + base + t];
    v[t] = sum;
  }
}

// --------------------------------------------------------------- passB ----
// Block: one matrix, 128 f-cols, all 4096 h-rows; 4 chunks of 1024 rows,
// 4 waves x 256 rows each. NT branch on c<=8. Dynamic 64 KB LDS; reduce
// scratch reuses the stage buffer.
__global__ __launch_bounds__(256) void passB14_kernel(const float* __restrict__ W1,
                                                      const float* __restrict__ W3,
                                                      const float* __restrict__ xseg,
                                                      float* __restrict__ h1seg,
                                                      float* __restrict__ h3seg,
                                                      const int* __restrict__ cnt,
                                                      const int* __restrict__ ord) {
  extern __shared__ float lds[];  // 64 KB
  int gy = blockIdx.y;
  int s = ord[gy >> 1];
  int mat = gy & 1;
  int c = cnt[s];
  if (c == 0) return;
  int e = s >> 1;
  int tid = threadIdx.x;
  int l = tid & 63;
  int w = tid >> 6;
  int colbase = blockIdx.x * 128;
  const float* Wbase = (mat ? W3 : W1) + (size_t)e * HH * FF + colbase;
  const float* xsrc = xseg + (size_t)s * HH * TSEG;
  float* segbase = (mat ? h3seg : h1seg) + ((size_t)s * FF + colbase) * TSEG;
  if (c <= 8) {
    const float2* wp2 = (const float2*)Wbase + l;
    float2 acc[8];
#pragma unroll
    for (int t = 0; t < 8; ++t) acc[t] = make_float2(0.f, 0.f);
    for (int ch = 0; ch < HH / CH; ++ch) {
      __syncthreads();
      stage1024(lds, xsrc + (size_t)(ch * CH) * TSEG, tid);
      __syncthreads();
      accum256_8(acc, wp2 + (size_t)(ch * CH + w * 256) * 2048,
                 lds + (w * 256) * TSEG);
    }
    __syncthreads();
    red_write8(lds, acc, tid);
    __syncthreads();
    if (tid < 128) {
      float v[8];
      red_read8(lds, v, tid);
      float* seg = segbase + (size_t)tid * TSEG;
      *(float4*)(seg) = *(const float4*)&v[0];
      *(float4*)(seg + 4) = *(const float4*)&v[4];
    }
  } else {
    const float* Wm = Wbase + (l & 31) * 4;
    int half8 = (l >> 5) * 8;
    float4 acc[8];
#pragma unroll
    for (int t = 0; t < 8; ++t) acc[t] = make_float4(0.f, 0.f, 0.f, 0.f);
    for (int ch = 0; ch < HH / CH; ++ch) {
      __syncthreads();
      stage1024(lds, xsrc + (size_t)(ch * CH) * TSEG, tid);
      __syncthreads();
      const float4* wp4 = (const float4*)(Wm + (size_t)(ch * CH + w * 256) * FF);
      accum256(acc, wp4, lds + (w * 256) * TSEG, half8);
    }
    __syncthreads();
    red_write(lds, acc, tid);
    __syncthreads();
    float v[8];
    red_read(lds, v, tid);
    int col = tid & 127;
    int half = tid >> 7;
    float* seg = segbase + (size_t)col * TSEG + half * 8;
    *(float4*)(seg) = *(const float4*)&v[0];
    *(float4*)(seg + 4) = *(const float4*)&v[4];
  }
}

// --------------------------------------------------------------- passC ----
// Block: 128 h-cols, rows [z*2048,+2048) of W2 (2 chunks of 1024); silu
// fused in staging; NT branch mirrors passB; tok/wts read from global in
// the epilogue (LDS budget = stage buffer only).
__global__ __launch_bounds__(256) void passC14_kernel(const float* __restrict__ W2,
                                                      const float* __restrict__ h1seg,
                                                      const float* __restrict__ h3seg,
                                                      const int* __restrict__ cnt,
                                                      const int* __restrict__ tok,
                                                      const float* __restrict__ wts,
                                                      const int* __restrict__ ord,
                                                      float* __restrict__ out) {
  extern __shared__ float lds[];  // 64 KB
  int gy = blockIdx.y;
  int s = ord[gy >> 1];
  int z = gy & 1;
  int c = cnt[s];
  if (c == 0) return;
  int e = s >> 1;
  int tid = threadIdx.x;
  int l = tid & 63;
  int w = tid >> 6;
  int colbase = blockIdx.x * 128;
  const float* Wbase = W2 + (size_t)e * FF * HH + (size_t)(z * 2048) * HH + colbase;
  const float* h1src = h1seg + ((size_t)s * FF + z * 2048) * TSEG;
  const float* h3src = h3seg + ((size_t)s * FF + z * 2048) * TSEG;
  if (c <= 8) {
    const float2* wp2 = (const float2*)Wbase + l;
    float2 acc[8];
#pragma unroll
    for (int t = 0; t < 8; ++t) acc[t] = make_float2(0.f, 0.f);
    for (int ch = 0; ch < 2; ++ch) {
      __syncthreads();
      stage_silu1024(lds, h1src + (size_t)(ch * CH) * TSEG,
                     h3src + (size_t)(ch * CH) * TSEG, tid);
      __syncthreads();
      accum256_8(acc, wp2 + (size_t)(ch * CH + w * 256) * 2048,
                 lds + (w * 256) * TSEG);
    }
    __syncthreads();
    red_write8(lds, acc, tid);
    __syncthreads();
    if (tid < 128) {
      float v[8];
      red_read8(lds, v, tid);
      float* op = out + colbase + tid;
#pragma unroll
      for (int t = 0; t < 8; ++t) {
        if (t < c) atomicAdd(op + (size_t)tok[s * TSEG + t] * HH,
                             wts[s * TSEG + t] * v[t]);
      }
    }
  } else {
    const float* Wm = Wbase + (l & 31) * 4;
    int half8 = (l >> 5) * 8;
    float4 acc[8];
#pragma unroll
    for (int t = 0; t < 8; ++t) acc[t] = make_float4(0.f, 0.f, 0.f, 0.f);
    for (int ch = 0; ch < 2; ++ch) {
      __syncthreads();
      stage_silu1024(lds, h1src + (size_t)(ch * CH) * TSEG,
                     h3src + (size_t)(ch * CH) * TSEG, tid);
      __syncthreads();
      const float4* wp4 = (const float4*)(Wm + (size_t)(ch * CH + w * 256) * HH);
      accum256(acc, wp4, lds + (w * 256) * TSEG, half8);
    }
    __syncthreads();
    red_write(lds, acc, tid);
    __syncthreads();
    float v[8];
    red_read(lds, v, tid);
    int col = tid & 127;
    int half = tid >> 7;
    float* op = out + colbase + col;
#pragma unroll
    for (int t = 0; t < 8; ++t) {
      int tt = half * 8 + t;
      if (tt < c) atomicAdd(op + (size_t)tok[s * TSEG + tt] * HH,
                            wts[s * TSEG + tt] * v[t]);
    }
  }
}

// -------------------------------------------------------------- launch ----
extern "C" void kernel_launch(void* const* d_in, const int* in_sizes, int n_in,
                              void* d_out, int out_size, void* d_ws, size_t ws_size,
                              hipStream_t stream) {
  const float* x  = (const float*)d_in[0];
  const float* Wg = (const float*)d_in[1];
  const float* W1 = (const float*)d_in[2];
  const float* W3 = (const float*)d_in[3];
  const float* W2 = (const float*)d_in[4];
  float* out = (float*)d_out;

  char* ws = (char*)d_ws;
  float* logits = (float*)ws;                 // 256 f32
  int*   cnt    = (int*)(ws + 1024);          // 16 i32
  int*   tok    = (int*)(ws + 1088);          // 256 i32
  float* wts    = (float*)(ws + 2112);        // 256 f32
  int*   ord    = (int*)(ws + 3136);          // 16 i32
  float* xseg   = (float*)(ws + 4096);                 // 4 MB
  float* h1seg  = xseg + (size_t)NSLOT * HH * TSEG;    // 4 MB
  float* h3seg  = h1seg + (size_t)NSLOT * FF * TSEG;   // 4 MB

  hipMemsetAsync(d_out, 0, (size_t)out_size * sizeof(float), stream);
  gate_kernel<<<BB, 256, 0, stream>>>(x, Wg, logits);
  route_kernel<<<1, 64, 0, stream>>>(logits, cnt, tok, wts, ord);
  buildx_kernel<<<dim3(HH / 256, NSLOT), 256, 0, stream>>>(x, cnt, tok, xseg);
  passB14_kernel<<<dim3(FF / 128, NSLOT * 2), 256, LDSB, stream>>>(W1, W3, xseg, h1seg, h3seg, cnt, ord);
  passC14_kernel<<<dim3(HH / 128, NSLOT * 2), 256, LDSB, stream>>>(W2, h1seg, h3seg, cnt, tok, wts, ord, out);
}